// Round 5
// baseline (994.062 us; speedup 1.0000x reference)
//
#include <hip/hip_runtime.h>
#include <hip/hip_bf16.h>
#include <cmath>

#define DEV __device__ __forceinline__

using bf16x8 = __attribute__((ext_vector_type(8))) short;
using f32x4  = __attribute__((ext_vector_type(4))) float;

static constexpr int B_ = 4, T_ = 2048, D_ = 1024, F_ = 4096, H_ = 16, HD_ = 64;
static constexpr int M_ = B_ * T_;  // 8192 rows

DEV unsigned short f2b(float f) {
  __hip_bfloat16 h = __float2bfloat16(f);
  return *reinterpret_cast<unsigned short*>(&h);
}
DEV float b2f(unsigned short u) {
  __hip_bfloat16 h;
  *reinterpret_cast<unsigned short*>(&h) = u;
  return __bfloat162float(h);
}

// async global->LDS, 16B per lane. LDS dest is wave-uniform base + lane*16.
DEV void gl16(const unsigned short* g, unsigned short* l) {
  __builtin_amdgcn_global_load_lds(
      (const __attribute__((address_space(1))) void*)g,
      (__attribute__((address_space(3))) void*)l, 16, 0, 0);
}

// ---------------- weight transpose + f32->bf16 convert ----------------
// W: (K x N) f32 row-major  ->  WT: (N x K) bf16 row-major
__global__ __launch_bounds__(256) void k_transpose_cvt(
    const float* __restrict__ W, unsigned short* __restrict__ WT, int K, int N) {
  __shared__ float tile[32][33];
  int bk = blockIdx.x * 32, bn = blockIdx.y * 32;
  int tx = threadIdx.x & 31, ty = threadIdx.x >> 5;  // ty 0..7
#pragma unroll
  for (int r = ty; r < 32; r += 8)
    tile[r][tx] = W[(size_t)(bk + r) * N + bn + tx];
  __syncthreads();
#pragma unroll
  for (int r = ty; r < 32; r += 8)
    WT[(size_t)(bn + r) * K + bk + tx] = f2b(tile[tx][r]);
}

// ---------------- LayerNorm (f32 in, bf16 out), one block per row ----------------
__global__ __launch_bounds__(256) void k_layernorm(
    const float* __restrict__ x, const float* __restrict__ sc,
    const float* __restrict__ bi, unsigned short* __restrict__ out) {
  int row = blockIdx.x;
  const float* xr = x + (size_t)row * D_;
  float4 v = reinterpret_cast<const float4*>(xr)[threadIdx.x];
  float s  = v.x + v.y + v.z + v.w;
  float s2 = v.x * v.x + v.y * v.y + v.z * v.z + v.w * v.w;
#pragma unroll
  for (int off = 1; off < 64; off <<= 1) {
    s  += __shfl_xor(s, off);
    s2 += __shfl_xor(s2, off);
  }
  __shared__ float red[2][4];
  int wid = threadIdx.x >> 6;
  if ((threadIdx.x & 63) == 0) { red[0][wid] = s; red[1][wid] = s2; }
  __syncthreads();
  s  = red[0][0] + red[0][1] + red[0][2] + red[0][3];
  s2 = red[1][0] + red[1][1] + red[1][2] + red[1][3];
  float mu  = s * (1.0f / D_);
  float var = s2 * (1.0f / D_) - mu * mu;
  float rstd = rsqrtf(var + 1e-6f);
  int c = threadIdx.x * 4;
  float o0 = (v.x - mu) * rstd * sc[c + 0] + bi[c + 0];
  float o1 = (v.y - mu) * rstd * sc[c + 1] + bi[c + 1];
  float o2 = (v.z - mu) * rstd * sc[c + 2] + bi[c + 2];
  float o3 = (v.w - mu) * rstd * sc[c + 3] + bi[c + 3];
  unsigned short* orow = out + (size_t)row * D_ + c;
  orow[0] = f2b(o0); orow[1] = f2b(o1); orow[2] = f2b(o2); orow[3] = f2b(o3);
}

// ---------------- RoPE in-place on q,k halves of packed qkv (bf16) ----------------
__global__ __launch_bounds__(256) void k_rope(
    unsigned short* __restrict__ qkv, const float* __restrict__ cosp,
    const float* __restrict__ sinp) {
  int idx = blockIdx.x * blockDim.x + threadIdx.x;  // B*T*H*32 pairs
  if (idx >= B_ * T_ * H_ * 32) return;
  int d = idx & 31;
  int h = (idx >> 5) & 15;
  int t = (idx >> 9) & 2047;
  int b = idx >> 20;
  float c  = cosp[t * 32 + d];
  float sn = sinp[t * 32 + d];
  size_t base = ((size_t)(b * T_ + t)) * 3072 + h * 64;
  unsigned short* qp = qkv + base;
  float x1 = b2f(qp[d]), x2 = b2f(qp[d + 32]);
  qp[d]      = f2b(x1 * c - x2 * sn);
  qp[d + 32] = f2b(x2 * c + x1 * sn);
  unsigned short* kp = qkv + base + 1024;
  x1 = b2f(kp[d]); x2 = b2f(kp[d + 32]);
  kp[d]      = f2b(x1 * c - x2 * sn);
  kp[d + 32] = f2b(x2 * c + x1 * sn);
}

// ---------------- MFMA flash attention ----------------
// Grid: (T/128, B*H). Block: 256 thr = 4 waves. Each wave owns 32 q-rows
// (2 row-tiles of 16). KV tiles of 64 keys, causal skip per wave.
__global__ __launch_bounds__(256) void k_attn_mfma(
    const unsigned short* __restrict__ qkv, unsigned short* __restrict__ out) {
  __shared__ __align__(16) unsigned short Kl[64][72];
  __shared__ __align__(16) unsigned short Vt[64][72];
  __shared__ __align__(16) unsigned short Pl[128][72];
  int bh = blockIdx.y, b = bh >> 4, h = bh & 15;
  int i0 = blockIdx.x * 128;
  int tid = threadIdx.x, lane = tid & 63, w = tid >> 6;
  int wrow = w * 32;
  int qr = lane & 15, qc = (lane >> 4) * 8;

  // Q fragments (A-layout): [row-tile][k-step], loaded once
  bf16x8 qf[2][2];
  const unsigned short* qbase = qkv + (size_t)(b * T_ + i0 + wrow) * 3072 + h * 64;
#pragma unroll
  for (int rt = 0; rt < 2; ++rt)
#pragma unroll
    for (int ks = 0; ks < 2; ++ks)
      qf[rt][ks] = *reinterpret_cast<const bf16x8*>(
          qbase + (size_t)(rt * 16 + qr) * 3072 + ks * 32 + qc);

  f32x4 o[2][4] = {};        // [rt][d-tile]
  float mrow[2][4], lrow[2][4];
#pragma unroll
  for (int rt = 0; rt < 2; ++rt)
#pragma unroll
    for (int r = 0; r < 4; ++r) { mrow[rt][r] = -1e30f; lrow[rt][r] = 0.f; }

  const unsigned short* kbase = qkv + (size_t)b * T_ * 3072 + 1024 + h * 64;
  const unsigned short* vbase = kbase + 1024;
  int ntile = i0 / 64 + 2;   // covers j0 <= i0+127

  for (int jt = 0; jt < ntile; ++jt) {
    int j0 = jt * 64;
    __syncthreads();
    // stage K row-major and V transposed (each thread: 2 chunks of 16B each)
#pragma unroll
    for (int c = 0; c < 2; ++c) {
      int chunk = tid + c * 256;
      int j = chunk >> 3, d0 = (chunk & 7) * 8;
      uint4 kk = *reinterpret_cast<const uint4*>(kbase + (size_t)(j0 + j) * 3072 + d0);
      *reinterpret_cast<uint4*>(&Kl[j][d0]) = kk;
      uint4 vv = *reinterpret_cast<const uint4*>(vbase + (size_t)(j0 + j) * 3072 + d0);
      const unsigned short* vp = reinterpret_cast<const unsigned short*>(&vv);
#pragma unroll
      for (int e = 0; e < 8; ++e) Vt[d0 + e][j] = vp[e];
    }
    __syncthreads();
    if (j0 > i0 + wrow + 31) continue;  // wave fully masked (barriers already passed)

    // ---- S = Q @ K^T ----
    bf16x8 kf[4][2];
#pragma unroll
    for (int ct = 0; ct < 4; ++ct)
#pragma unroll
      for (int ks = 0; ks < 2; ++ks)
        kf[ct][ks] = *reinterpret_cast<const bf16x8*>(&Kl[ct * 16 + qr][ks * 32 + qc]);
    f32x4 s[2][4];
#pragma unroll
    for (int rt = 0; rt < 2; ++rt)
#pragma unroll
      for (int ct = 0; ct < 4; ++ct) {
        f32x4 acc = {};
#pragma unroll
        for (int ks = 0; ks < 2; ++ks)
          acc = __builtin_amdgcn_mfma_f32_16x16x32_bf16(qf[rt][ks], kf[ct][ks], acc, 0, 0, 0);
        s[rt][ct] = acc;
      }

    // ---- online softmax (C-layout: row=(lane>>4)*4+r, col=lane&15) ----
#pragma unroll
    for (int rt = 0; rt < 2; ++rt) {
#pragma unroll
      for (int r = 0; r < 4; ++r) {
        int gi = i0 + wrow + rt * 16 + ((lane >> 4) << 2) + r;
        float mx = -1e30f;
#pragma unroll
        for (int ct = 0; ct < 4; ++ct) {
          int gj = j0 + ct * 16 + (lane & 15);
          float v = s[rt][ct][r] * 0.125f;
          v = (gj <= gi) ? v : -1e30f;
          s[rt][ct][r] = v;
          mx = fmaxf(mx, v);
        }
#pragma unroll
        for (int off = 1; off < 16; off <<= 1) mx = fmaxf(mx, __shfl_xor(mx, off));
        float mn = fmaxf(mrow[rt][r], mx);
        float sc = __expf(mrow[rt][r] - mn);
        mrow[rt][r] = mn;
        float rs = 0.f;
#pragma unroll
        for (int ct = 0; ct < 4; ++ct) {
          float p = __expf(s[rt][ct][r] - mn);
          s[rt][ct][r] = p;
          rs += p;
        }
#pragma unroll
        for (int off = 1; off < 16; off <<= 1) rs += __shfl_xor(rs, off);
        lrow[rt][r] = lrow[rt][r] * sc + rs;
#pragma unroll
        for (int dt = 0; dt < 4; ++dt) o[rt][dt][r] *= sc;
      }
    }

    // ---- P -> LDS (bf16), then PV ----
#pragma unroll
    for (int rt = 0; rt < 2; ++rt)
#pragma unroll
      for (int ct = 0; ct < 4; ++ct)
#pragma unroll
        for (int r = 0; r < 4; ++r)
          Pl[wrow + rt * 16 + ((lane >> 4) << 2) + r][ct * 16 + (lane & 15)] =
              f2b(s[rt][ct][r]);
#pragma unroll
    for (int ks = 0; ks < 2; ++ks) {
      bf16x8 vf[4];
#pragma unroll
      for (int dt = 0; dt < 4; ++dt)
        vf[dt] = *reinterpret_cast<const bf16x8*>(&Vt[dt * 16 + qr][ks * 32 + qc]);
#pragma unroll
      for (int rt = 0; rt < 2; ++rt) {
        bf16x8 pf = *reinterpret_cast<const bf16x8*>(&Pl[wrow + rt * 16 + qr][ks * 32 + qc]);
#pragma unroll
        for (int dt = 0; dt < 4; ++dt)
          o[rt][dt] = __builtin_amdgcn_mfma_f32_16x16x32_bf16(pf, vf[dt], o[rt][dt], 0, 0, 0);
      }
    }
  }

  // ---- write O / l ----
#pragma unroll
  for (int rt = 0; rt < 2; ++rt)
#pragma unroll
    for (int r = 0; r < 4; ++r) {
      float inv = 1.0f / lrow[rt][r];
      size_t grow = (size_t)(b * T_ + i0 + wrow + rt * 16 + ((lane >> 4) << 2) + r);
#pragma unroll
      for (int dt = 0; dt < 4; ++dt)
        out[grow * 1024 + h * 64 + dt * 16 + (lane & 15)] = f2b(o[rt][dt][r] * inv);
    }
}

// ---------------- MFMA GEMM: C(MxN) = A(MxK) @ Bt(NxK)^T, bf16 in, f32 acc ----------
// m97 structure: global_load_lds width-16 staging into LINEAR [128][64] LDS
// (no pad — gload_lds writes base+lane*16; 16-way ds_read conflict is hidden
//  behind the stage+vmcnt+barrier critical path at this 2-barrier structure).
// MODE 0: C = bf16(acc)
// MODE 1: C(f32) = res + acc * gamma[col]
// MODE 2: dual-B: C = bf16( gelu_tanh(accB) * accB2 )
template <int MODE>
__global__ __launch_bounds__(256) void k_gemm(
    const unsigned short* __restrict__ A, const unsigned short* __restrict__ Bt,
    const unsigned short* __restrict__ Bt2, void* __restrict__ Cout,
    const float* __restrict__ res, const float* __restrict__ gamma,
    int M, int N, int K) {
  __shared__ __align__(16) unsigned short Al[128][64];
  __shared__ __align__(16) unsigned short Bl[128][64];
  __shared__ __align__(16) unsigned short Bl2[(MODE == 2) ? 128 : 1][64];
  int m0 = blockIdx.y * 128, n0 = blockIdx.x * 128;
  int tid = threadIdx.x, lane = tid & 63, w = tid >> 6;
  int wm = (w >> 1) * 64, wn = (w & 1) * 64;
  // staging: chunk = w*4+it covers LDS bytes [chunk*1024, +1024) = rows chunk*8..+7.
  // HW writes lane l at chunk base + l*16 -> row chunk*8 + l/8, col (l&7)*8.
  int srow = lane >> 3, scol = (lane & 7) * 8;
  f32x4 acc[4][4] = {};
  f32x4 acc2[4][4] = {};
  for (int k0 = 0; k0 < K; k0 += 64) {
#pragma unroll
    for (int it = 0; it < 4; ++it) {
      int chunk = w * 4 + it;
      int row = chunk * 8 + srow;
      gl16(A  + (size_t)(m0 + row) * K + k0 + scol, &Al[0][0] + chunk * 512);
      gl16(Bt + (size_t)(n0 + row) * K + k0 + scol, &Bl[0][0] + chunk * 512);
      if constexpr (MODE == 2)
        gl16(Bt2 + (size_t)(n0 + row) * K + k0 + scol, &Bl2[0][0] + chunk * 512);
    }
    __syncthreads();  // compiler drains vmcnt(0) before s_barrier -> tile ready
#pragma unroll
    for (int kk = 0; kk < 2; ++kk) {
      int krow = kk * 32 + ((lane >> 4) << 3);
      bf16x8 af[4], bv[4];
#pragma unroll
      for (int i = 0; i < 4; ++i)
        af[i] = *reinterpret_cast<const bf16x8*>(&Al[wm + i * 16 + (lane & 15)][krow]);
#pragma unroll
      for (int j = 0; j < 4; ++j)
        bv[j] = *reinterpret_cast<const bf16x8*>(&Bl[wn + j * 16 + (lane & 15)][krow]);
#pragma unroll
      for (int i = 0; i < 4; ++i)
#pragma unroll
        for (int j = 0; j < 4; ++j)
          acc[i][j] = __builtin_amdgcn_mfma_f32_16x16x32_bf16(af[i], bv[j], acc[i][j], 0, 0, 0);
      if constexpr (MODE == 2) {
#pragma unroll
        for (int j = 0; j < 4; ++j)
          bv[j] = *reinterpret_cast<const bf16x8*>(&Bl2[wn + j * 16 + (lane & 15)][krow]);
#pragma unroll
        for (int i = 0; i < 4; ++i)
#pragma unroll
          for (int j = 0; j < 4; ++j)
            acc2[i][j] = __builtin_amdgcn_mfma_f32_16x16x32_bf16(af[i], bv[j], acc2[i][j], 0, 0, 0);
      }
    }
    __syncthreads();
  }
#pragma unroll
  for (int i = 0; i < 4; ++i) {
#pragma unroll
    for (int j = 0; j < 4; ++j) {
      int row0 = m0 + wm + i * 16 + ((lane >> 4) << 2);
      int col  = n0 + wn + j * 16 + (lane & 15);
#pragma unroll
      for (int r = 0; r < 4; ++r) {
        float va = acc[i][j][r];
        size_t off = (size_t)(row0 + r) * N + col;
        if constexpr (MODE == 0) {
          ((unsigned short*)Cout)[off] = f2b(va);
        } else if constexpr (MODE == 1) {
          ((float*)Cout)[off] = res[off] + va * gamma[col];
        } else {
          float u = acc2[i][j][r];
          float t = tanhf(0.7978845608f * (va + 0.044715f * va * va * va));
          ((unsigned short*)Cout)[off] = f2b(0.5f * va * (1.0f + t) * u);
        }
      }
    }
  }
}

extern "C" void kernel_launch(void* const* d_in, const int* in_sizes, int n_in,
                              void* d_out, int out_size, void* d_ws, size_t ws_size,
                              hipStream_t stream) {
  const float* x      = (const float*)d_in[0];
  const float* cosp   = (const float*)d_in[1];
  const float* sinp   = (const float*)d_in[2];
  const float* ln1s   = (const float*)d_in[3];
  const float* ln1b   = (const float*)d_in[4];
  const float* w_qkv  = (const float*)d_in[5];
  const float* w_o    = (const float*)d_in[6];
  const float* g_attn = (const float*)d_in[7];
  const float* ln2s   = (const float*)d_in[8];
  const float* ln2b   = (const float*)d_in[9];
  const float* w_gate = (const float*)d_in[10];
  const float* w_up   = (const float*)d_in[11];
  const float* w_down = (const float*)d_in[12];
  const float* g_mlp  = (const float*)d_in[13];
  float* outp = (float*)d_out;

  char* ws = (char*)d_ws;
  unsigned short* wqkvT = (unsigned short*)(ws + 0);         // 3072x1024 bf16, 6MB
  unsigned short* woT   = (unsigned short*)(ws + 6291456);   // 1024x1024, 2MB
  unsigned short* wgT   = (unsigned short*)(ws + 8388608);   // 4096x1024, 8MB
  unsigned short* wuT   = (unsigned short*)(ws + 16777216);  // 4096x1024, 8MB
  unsigned short* wdT   = (unsigned short*)(ws + 25165824);  // 1024x4096, 8MB
  float* x2             = (float*)(ws + 33554432);           // 8192x1024 f32, 32MB
  unsigned short* h2    = (unsigned short*)(ws + 67108864);  // 8192x1024, 16MB
  char* big = ws + 83886080;
  unsigned short* hbf     = (unsigned short*)(big);               // 16MB
  unsigned short* qkv     = (unsigned short*)(big + 16777216);    // 48MB
  unsigned short* attnout = (unsigned short*)(big + 67108864);    // 16MB
  unsigned short* mbuf    = (unsigned short*)(big);               // 64MB, reuses h/qkv
  // total ws use: 160MB

  // weights -> bf16 transposed
  k_transpose_cvt<<<dim3(32, 96), 256, 0, stream>>>(w_qkv, wqkvT, 1024, 3072);
  k_transpose_cvt<<<dim3(32, 32), 256, 0, stream>>>(w_o, woT, 1024, 1024);
  k_transpose_cvt<<<dim3(32, 128), 256, 0, stream>>>(w_gate, wgT, 1024, 4096);
  k_transpose_cvt<<<dim3(32, 128), 256, 0, stream>>>(w_up, wuT, 1024, 4096);
  k_transpose_cvt<<<dim3(128, 32), 256, 0, stream>>>(w_down, wdT, 4096, 1024);

  // LN1 -> h (bf16)
  k_layernorm<<<M_, 256, 0, stream>>>(x, ln1s, ln1b, hbf);
  // qkv = h @ w_qkv
  k_gemm<0><<<dim3(3072 / 128, M_ / 128), 256, 0, stream>>>(
      hbf, wqkvT, nullptr, qkv, nullptr, nullptr, M_, 3072, 1024);
  // RoPE in-place on q,k
  k_rope<<<16384, 256, 0, stream>>>(qkv, cosp, sinp);
  // MFMA flash attention
  k_attn_mfma<<<dim3(T_ / 128, B_ * H_), 256, 0, stream>>>(qkv, attnout);
  // x2 = x + (attnout @ w_o) * gamma_attn
  k_gemm<1><<<dim3(1024 / 128, M_ / 128), 256, 0, stream>>>(
      attnout, woT, nullptr, x2, x, g_attn, M_, 1024, 1024);
  // LN2 -> h2
  k_layernorm<<<M_, 256, 0, stream>>>(x2, ln2s, ln2b, h2);
  // m = gelu(h2@w_gate) * (h2@w_up)
  k_gemm<2><<<dim3(4096 / 128, M_ / 128), 256, 0, stream>>>(
      h2, wgT, wuT, mbuf, nullptr, nullptr, M_, 4096, 1024);
  // out = x2 + (m @ w_down) * gamma_mlp
  k_gemm<1><<<dim3(1024 / 128, M_ / 128), 256, 0, stream>>>(
      mbuf, wdT, nullptr, outp, x2, g_mlp, M_, 1024, 4096);
}

// Round 6
// 922.128 us; speedup vs baseline: 1.0780x; 1.0780x over previous
//
#include <hip/hip_runtime.h>
#include <hip/hip_bf16.h>
#include <cmath>

#define DEV __device__ __forceinline__

using bf16x8 = __attribute__((ext_vector_type(8))) short;
using f32x4  = __attribute__((ext_vector_type(4))) float;

static constexpr int B_ = 4, T_ = 2048, D_ = 1024, F_ = 4096, H_ = 16, HD_ = 64;
static constexpr int M_ = B_ * T_;  // 8192 rows

DEV unsigned short f2b(float f) {
  __hip_bfloat16 h = __float2bfloat16(f);
  return *reinterpret_cast<unsigned short*>(&h);
}
DEV float b2f(unsigned short u) {
  __hip_bfloat16 h;
  *reinterpret_cast<unsigned short*>(&h) = u;
  return __bfloat162float(h);
}

// async global->LDS, 16B per lane. LDS dest is wave-uniform base + lane*16.
DEV void gl16(const unsigned short* g, unsigned short* l) {
  __builtin_amdgcn_global_load_lds(
      (const __attribute__((address_space(1))) void*)g,
      (__attribute__((address_space(3))) void*)l, 16, 0, 0);
}

// ---------------- weight transpose + f32->bf16 convert ----------------
// W: (K x N) f32 row-major  ->  WT: (N x K) bf16 row-major
__global__ __launch_bounds__(256) void k_transpose_cvt(
    const float* __restrict__ W, unsigned short* __restrict__ WT, int K, int N) {
  __shared__ float tile[32][33];
  int bk = blockIdx.x * 32, bn = blockIdx.y * 32;
  int tx = threadIdx.x & 31, ty = threadIdx.x >> 5;  // ty 0..7
#pragma unroll
  for (int r = ty; r < 32; r += 8)
    tile[r][tx] = W[(size_t)(bk + r) * N + bn + tx];
  __syncthreads();
#pragma unroll
  for (int r = ty; r < 32; r += 8)
    WT[(size_t)(bn + r) * K + bk + tx] = f2b(tile[tx][r]);
}

// ---------------- LayerNorm (f32 in, bf16 out), one block per row ----------------
__global__ __launch_bounds__(256) void k_layernorm(
    const float* __restrict__ x, const float* __restrict__ sc,
    const float* __restrict__ bi, unsigned short* __restrict__ out) {
  int row = blockIdx.x;
  const float* xr = x + (size_t)row * D_;
  float4 v = reinterpret_cast<const float4*>(xr)[threadIdx.x];
  float s  = v.x + v.y + v.z + v.w;
  float s2 = v.x * v.x + v.y * v.y + v.z * v.z + v.w * v.w;
#pragma unroll
  for (int off = 1; off < 64; off <<= 1) {
    s  += __shfl_xor(s, off);
    s2 += __shfl_xor(s2, off);
  }
  __shared__ float red[2][4];
  int wid = threadIdx.x >> 6;
  if ((threadIdx.x & 63) == 0) { red[0][wid] = s; red[1][wid] = s2; }
  __syncthreads();
  s  = red[0][0] + red[0][1] + red[0][2] + red[0][3];
  s2 = red[1][0] + red[1][1] + red[1][2] + red[1][3];
  float mu  = s * (1.0f / D_);
  float var = s2 * (1.0f / D_) - mu * mu;
  float rstd = rsqrtf(var + 1e-6f);
  int c = threadIdx.x * 4;
  float o0 = (v.x - mu) * rstd * sc[c + 0] + bi[c + 0];
  float o1 = (v.y - mu) * rstd * sc[c + 1] + bi[c + 1];
  float o2 = (v.z - mu) * rstd * sc[c + 2] + bi[c + 2];
  float o3 = (v.w - mu) * rstd * sc[c + 3] + bi[c + 3];
  unsigned short* orow = out + (size_t)row * D_ + c;
  orow[0] = f2b(o0); orow[1] = f2b(o1); orow[2] = f2b(o2); orow[3] = f2b(o3);
}

// ---------------- RoPE in-place on q,k halves of packed qkv (bf16) ----------------
__global__ __launch_bounds__(256) void k_rope(
    unsigned short* __restrict__ qkv, const float* __restrict__ cosp,
    const float* __restrict__ sinp) {
  int idx = blockIdx.x * blockDim.x + threadIdx.x;  // B*T*H*32 pairs
  if (idx >= B_ * T_ * H_ * 32) return;
  int d = idx & 31;
  int h = (idx >> 5) & 15;
  int t = (idx >> 9) & 2047;
  int b = idx >> 20;
  float c  = cosp[t * 32 + d];
  float sn = sinp[t * 32 + d];
  size_t base = ((size_t)(b * T_ + t)) * 3072 + h * 64;
  unsigned short* qp = qkv + base;
  float x1 = b2f(qp[d]), x2 = b2f(qp[d + 32]);
  qp[d]      = f2b(x1 * c - x2 * sn);
  qp[d + 32] = f2b(x2 * c + x1 * sn);
  unsigned short* kp = qkv + base + 1024;
  x1 = b2f(kp[d]); x2 = b2f(kp[d + 32]);
  kp[d]      = f2b(x1 * c - x2 * sn);
  kp[d + 32] = f2b(x2 * c + x1 * sn);
}

// ---------------- MFMA flash attention ----------------
// Grid: (T/128, B*H). Block: 256 thr = 4 waves. Each wave owns 32 q-rows
// (2 row-tiles of 16). KV tiles of 64 keys, causal skip per wave.
__global__ __launch_bounds__(256) void k_attn_mfma(
    const unsigned short* __restrict__ qkv, unsigned short* __restrict__ out) {
  __shared__ __align__(16) unsigned short Kl[64][72];
  __shared__ __align__(16) unsigned short Vt[64][72];
  __shared__ __align__(16) unsigned short Pl[128][72];
  int bh = blockIdx.y, b = bh >> 4, h = bh & 15;
  int i0 = blockIdx.x * 128;
  int tid = threadIdx.x, lane = tid & 63, w = tid >> 6;
  int wrow = w * 32;
  int qr = lane & 15, qc = (lane >> 4) * 8;

  // Q fragments (A-layout): [row-tile][k-step], loaded once
  bf16x8 qf[2][2];
  const unsigned short* qbase = qkv + (size_t)(b * T_ + i0 + wrow) * 3072 + h * 64;
#pragma unroll
  for (int rt = 0; rt < 2; ++rt)
#pragma unroll
    for (int ks = 0; ks < 2; ++ks)
      qf[rt][ks] = *reinterpret_cast<const bf16x8*>(
          qbase + (size_t)(rt * 16 + qr) * 3072 + ks * 32 + qc);

  f32x4 o[2][4] = {};        // [rt][d-tile]
  float mrow[2][4], lrow[2][4];
#pragma unroll
  for (int rt = 0; rt < 2; ++rt)
#pragma unroll
    for (int r = 0; r < 4; ++r) { mrow[rt][r] = -1e30f; lrow[rt][r] = 0.f; }

  const unsigned short* kbase = qkv + (size_t)b * T_ * 3072 + 1024 + h * 64;
  const unsigned short* vbase = kbase + 1024;
  int ntile = i0 / 64 + 2;   // covers j0 <= i0+127

  for (int jt = 0; jt < ntile; ++jt) {
    int j0 = jt * 64;
    __syncthreads();
    // stage K row-major and V transposed (each thread: 2 chunks of 16B each)
#pragma unroll
    for (int c = 0; c < 2; ++c) {
      int chunk = tid + c * 256;
      int j = chunk >> 3, d0 = (chunk & 7) * 8;
      uint4 kk = *reinterpret_cast<const uint4*>(kbase + (size_t)(j0 + j) * 3072 + d0);
      *reinterpret_cast<uint4*>(&Kl[j][d0]) = kk;
      uint4 vv = *reinterpret_cast<const uint4*>(vbase + (size_t)(j0 + j) * 3072 + d0);
      const unsigned short* vp = reinterpret_cast<const unsigned short*>(&vv);
#pragma unroll
      for (int e = 0; e < 8; ++e) Vt[d0 + e][j] = vp[e];
    }
    __syncthreads();
    if (j0 > i0 + wrow + 31) continue;  // wave fully masked (barriers already passed)

    // ---- S = Q @ K^T ----
    bf16x8 kf[4][2];
#pragma unroll
    for (int ct = 0; ct < 4; ++ct)
#pragma unroll
      for (int ks = 0; ks < 2; ++ks)
        kf[ct][ks] = *reinterpret_cast<const bf16x8*>(&Kl[ct * 16 + qr][ks * 32 + qc]);
    f32x4 s[2][4];
#pragma unroll
    for (int rt = 0; rt < 2; ++rt)
#pragma unroll
      for (int ct = 0; ct < 4; ++ct) {
        f32x4 acc = {};
#pragma unroll
        for (int ks = 0; ks < 2; ++ks)
          acc = __builtin_amdgcn_mfma_f32_16x16x32_bf16(qf[rt][ks], kf[ct][ks], acc, 0, 0, 0);
        s[rt][ct] = acc;
      }

    // ---- online softmax (C-layout: row=(lane>>4)*4+r, col=lane&15) ----
#pragma unroll
    for (int rt = 0; rt < 2; ++rt) {
#pragma unroll
      for (int r = 0; r < 4; ++r) {
        int gi = i0 + wrow + rt * 16 + ((lane >> 4) << 2) + r;
        float mx = -1e30f;
#pragma unroll
        for (int ct = 0; ct < 4; ++ct) {
          int gj = j0 + ct * 16 + (lane & 15);
          float v = s[rt][ct][r] * 0.125f;
          v = (gj <= gi) ? v : -1e30f;
          s[rt][ct][r] = v;
          mx = fmaxf(mx, v);
        }
#pragma unroll
        for (int off = 1; off < 16; off <<= 1) mx = fmaxf(mx, __shfl_xor(mx, off));
        float mn = fmaxf(mrow[rt][r], mx);
        float sc = __expf(mrow[rt][r] - mn);
        mrow[rt][r] = mn;
        float rs = 0.f;
#pragma unroll
        for (int ct = 0; ct < 4; ++ct) {
          float p = __expf(s[rt][ct][r] - mn);
          s[rt][ct][r] = p;
          rs += p;
        }
#pragma unroll
        for (int off = 1; off < 16; off <<= 1) rs += __shfl_xor(rs, off);
        lrow[rt][r] = lrow[rt][r] * sc + rs;
#pragma unroll
        for (int dt = 0; dt < 4; ++dt) o[rt][dt][r] *= sc;
      }
    }

    // ---- P -> LDS (bf16), then PV ----
#pragma unroll
    for (int rt = 0; rt < 2; ++rt)
#pragma unroll
      for (int ct = 0; ct < 4; ++ct)
#pragma unroll
        for (int r = 0; r < 4; ++r)
          Pl[wrow + rt * 16 + ((lane >> 4) << 2) + r][ct * 16 + (lane & 15)] =
              f2b(s[rt][ct][r]);
#pragma unroll
    for (int ks = 0; ks < 2; ++ks) {
      bf16x8 vf[4];
#pragma unroll
      for (int dt = 0; dt < 4; ++dt)
        vf[dt] = *reinterpret_cast<const bf16x8*>(&Vt[dt * 16 + qr][ks * 32 + qc]);
#pragma unroll
      for (int rt = 0; rt < 2; ++rt) {
        bf16x8 pf = *reinterpret_cast<const bf16x8*>(&Pl[wrow + rt * 16 + qr][ks * 32 + qc]);
#pragma unroll
        for (int dt = 0; dt < 4; ++dt)
          o[rt][dt] = __builtin_amdgcn_mfma_f32_16x16x32_bf16(pf, vf[dt], o[rt][dt], 0, 0, 0);
      }
    }
  }

  // ---- write O / l ----
#pragma unroll
  for (int rt = 0; rt < 2; ++rt)
#pragma unroll
    for (int r = 0; r < 4; ++r) {
      float inv = 1.0f / lrow[rt][r];
      size_t grow = (size_t)(b * T_ + i0 + wrow + rt * 16 + ((lane >> 4) << 2) + r);
#pragma unroll
      for (int dt = 0; dt < 4; ++dt)
        out[grow * 1024 + h * 64 + dt * 16 + (lane & 15)] = f2b(o[rt][dt][r] * inv);
    }
}

// ---------------- MFMA GEMM: C(MxN) = A(MxK) @ Bt(NxK)^T, bf16 in, f32 acc ----------
// global_load_lds width-16 staging into LINEAR [128][64] LDS with a both-sides
// involution swizzle (rule #21 / m201): LDS[row][slot] holds global
// [row][slot ^ (row&7)] (slot = 16B column unit). Stage pre-swizzles the
// GLOBAL source per-lane (HW writes LDS linearly); ds_read XORs the slot.
// Spreads the former 16-way read conflict to the 2-lanes/bank minimum.
// MODE 0: C = bf16(acc)
// MODE 1: C(f32) = res + acc * gamma[col]
// MODE 2: dual-B: C = bf16( gelu_tanh(accB) * accB2 )
template <int MODE>
__global__ __launch_bounds__(256) void k_gemm(
    const unsigned short* __restrict__ A, const unsigned short* __restrict__ Bt,
    const unsigned short* __restrict__ Bt2, void* __restrict__ Cout,
    const float* __restrict__ res, const float* __restrict__ gamma,
    int M, int N, int K) {
  __shared__ __align__(16) unsigned short Al[128][64];
  __shared__ __align__(16) unsigned short Bl[128][64];
  __shared__ __align__(16) unsigned short Bl2[(MODE == 2) ? 128 : 1][64];
  int m0 = blockIdx.y * 128, n0 = blockIdx.x * 128;
  int tid = threadIdx.x, lane = tid & 63, w = tid >> 6;
  int wm = (w >> 1) * 64, wn = (w & 1) * 64;
  // staging: chunk = w*4+it covers LDS rows chunk*8..+7 (1024 B). HW puts lane
  // l at chunk base + l*16 -> row chunk*8 + (l>>3), slot l&7. Source col-slot
  // is pre-swizzled: (l&7) ^ (l>>3)  (row&7 == l>>3 within a chunk).
  int srow = lane >> 3;
  int scol = ((lane & 7) ^ (lane >> 3)) * 8;
  f32x4 acc[4][4] = {};
  f32x4 acc2[4][4] = {};
  for (int k0 = 0; k0 < K; k0 += 64) {
#pragma unroll
    for (int it = 0; it < 4; ++it) {
      int chunk = w * 4 + it;
      int row = chunk * 8 + srow;
      gl16(A  + (size_t)(m0 + row) * K + k0 + scol, &Al[0][0] + chunk * 512);
      gl16(Bt + (size_t)(n0 + row) * K + k0 + scol, &Bl[0][0] + chunk * 512);
      if constexpr (MODE == 2)
        gl16(Bt2 + (size_t)(n0 + row) * K + k0 + scol, &Bl2[0][0] + chunk * 512);
    }
    __syncthreads();  // compiler drains vmcnt(0) before s_barrier -> tile ready
#pragma unroll
    for (int kk = 0; kk < 2; ++kk) {
      // fragment rows have (row&7) == (lane&7); un-swizzle the slot on read
      int slotA = ((kk * 4 + (lane >> 4)) ^ (lane & 7)) * 8;
      bf16x8 af[4], bv[4];
#pragma unroll
      for (int i = 0; i < 4; ++i)
        af[i] = *reinterpret_cast<const bf16x8*>(&Al[wm + i * 16 + (lane & 15)][slotA]);
#pragma unroll
      for (int j = 0; j < 4; ++j)
        bv[j] = *reinterpret_cast<const bf16x8*>(&Bl[wn + j * 16 + (lane & 15)][slotA]);
#pragma unroll
      for (int i = 0; i < 4; ++i)
#pragma unroll
        for (int j = 0; j < 4; ++j)
          acc[i][j] = __builtin_amdgcn_mfma_f32_16x16x32_bf16(af[i], bv[j], acc[i][j], 0, 0, 0);
      if constexpr (MODE == 2) {
#pragma unroll
        for (int j = 0; j < 4; ++j)
          bv[j] = *reinterpret_cast<const bf16x8*>(&Bl2[wn + j * 16 + (lane & 15)][slotA]);
#pragma unroll
        for (int i = 0; i < 4; ++i)
#pragma unroll
          for (int j = 0; j < 4; ++j)
            acc2[i][j] = __builtin_amdgcn_mfma_f32_16x16x32_bf16(af[i], bv[j], acc2[i][j], 0, 0, 0);
      }
    }
    __syncthreads();
  }
#pragma unroll
  for (int i = 0; i < 4; ++i) {
#pragma unroll
    for (int j = 0; j < 4; ++j) {
      int row0 = m0 + wm + i * 16 + ((lane >> 4) << 2);
      int col  = n0 + wn + j * 16 + (lane & 15);
#pragma unroll
      for (int r = 0; r < 4; ++r) {
        float va = acc[i][j][r];
        size_t off = (size_t)(row0 + r) * N + col;
        if constexpr (MODE == 0) {
          ((unsigned short*)Cout)[off] = f2b(va);
        } else if constexpr (MODE == 1) {
          ((float*)Cout)[off] = res[off] + va * gamma[col];
        } else {
          float u = acc2[i][j][r];
          float t = tanhf(0.7978845608f * (va + 0.044715f * va * va * va));
          ((unsigned short*)Cout)[off] = f2b(0.5f * va * (1.0f + t) * u);
        }
      }
    }
  }
}

extern "C" void kernel_launch(void* const* d_in, const int* in_sizes, int n_in,
                              void* d_out, int out_size, void* d_ws, size_t ws_size,
                              hipStream_t stream) {
  const float* x      = (const float*)d_in[0];
  const float* cosp   = (const float*)d_in[1];
  const float* sinp   = (const float*)d_in[2];
  const float* ln1s   = (const float*)d_in[3];
  const float* ln1b   = (const float*)d_in[4];
  const float* w_qkv  = (const float*)d_in[5];
  const float* w_o    = (const float*)d_in[6];
  const float* g_attn = (const float*)d_in[7];
  const float* ln2s   = (const float*)d_in[8];
  const float* ln2b   = (const float*)d_in[9];
  const float* w_gate = (const float*)d_in[10];
  const float* w_up   = (const float*)d_in[11];
  const float* w_down = (const float*)d_in[12];
  const float* g_mlp  = (const float*)d_in[13];
  float* outp = (float*)d_out;

  char* ws = (char*)d_ws;
  unsigned short* wqkvT = (unsigned short*)(ws + 0);         // 3072x1024 bf16, 6MB
  unsigned short* woT   = (unsigned short*)(ws + 6291456);   // 1024x1024, 2MB
  unsigned short* wgT   = (unsigned short*)(ws + 8388608);   // 4096x1024, 8MB
  unsigned short* wuT   = (unsigned short*)(ws + 16777216);  // 4096x1024, 8MB
  unsigned short* wdT   = (unsigned short*)(ws + 25165824);  // 1024x4096, 8MB
  float* x2             = (float*)(ws + 33554432);           // 8192x1024 f32, 32MB
  unsigned short* h2    = (unsigned short*)(ws + 67108864);  // 8192x1024, 16MB
  char* big = ws + 83886080;
  unsigned short* hbf     = (unsigned short*)(big);               // 16MB
  unsigned short* qkv     = (unsigned short*)(big + 16777216);    // 48MB
  unsigned short* attnout = (unsigned short*)(big + 67108864);    // 16MB
  unsigned short* mbuf    = (unsigned short*)(big);               // 64MB, reuses h/qkv
  // total ws use: 160MB

  // weights -> bf16 transposed
  k_transpose_cvt<<<dim3(32, 96), 256, 0, stream>>>(w_qkv, wqkvT, 1024, 3072);
  k_transpose_cvt<<<dim3(32, 32), 256, 0, stream>>>(w_o, woT, 1024, 1024);
  k_transpose_cvt<<<dim3(32, 128), 256, 0, stream>>>(w_gate, wgT, 1024, 4096);
  k_transpose_cvt<<<dim3(32, 128), 256, 0, stream>>>(w_up, wuT, 1024, 4096);
  k_transpose_cvt<<<dim3(128, 32), 256, 0, stream>>>(w_down, wdT, 4096, 1024);

  // LN1 -> h (bf16)
  k_layernorm<<<M_, 256, 0, stream>>>(x, ln1s, ln1b, hbf);
  // qkv = h @ w_qkv
  k_gemm<0><<<dim3(3072 / 128, M_ / 128), 256, 0, stream>>>(
      hbf, wqkvT, nullptr, qkv, nullptr, nullptr, M_, 3072, 1024);
  // RoPE in-place on q,k
  k_rope<<<16384, 256, 0, stream>>>(qkv, cosp, sinp);
  // MFMA flash attention
  k_attn_mfma<<<dim3(T_ / 128, B_ * H_), 256, 0, stream>>>(qkv, attnout);
  // x2 = x + (attnout @ w_o) * gamma_attn
  k_gemm<1><<<dim3(1024 / 128, M_ / 128), 256, 0, stream>>>(
      attnout, woT, nullptr, x2, x, g_attn, M_, 1024, 1024);
  // LN2 -> h2
  k_layernorm<<<M_, 256, 0, stream>>>(x2, ln2s, ln2b, h2);
  // m = gelu(h2@w_gate) * (h2@w_up)
  k_gemm<2><<<dim3(4096 / 128, M_ / 128), 256, 0, stream>>>(
      h2, wgT, wuT, mbuf, nullptr, nullptr, M_, 4096, 1024);
  // out = x2 + (m @ w_down) * gamma_mlp
  k_gemm<1><<<dim3(1024 / 128, M_ / 128), 256, 0, stream>>>(
      mbuf, wdT, nullptr, outp, x2, g_mlp, M_, 1024, 4096);
}

// Round 8
// 880.966 us; speedup vs baseline: 1.1284x; 1.0467x over previous
//
#include <hip/hip_runtime.h>
#include <hip/hip_bf16.h>
#include <cmath>

#define DEV __device__ __forceinline__

using bf16x8 = __attribute__((ext_vector_type(8))) short;
using f32x4  = __attribute__((ext_vector_type(4))) float;

static constexpr int B_ = 4, T_ = 2048, D_ = 1024, F_ = 4096, H_ = 16, HD_ = 64;
static constexpr int M_ = B_ * T_;  // 8192 rows

DEV unsigned short f2b(float f) {
  __hip_bfloat16 h = __float2bfloat16(f);
  return *reinterpret_cast<unsigned short*>(&h);
}
DEV float b2f(unsigned short u) {
  __hip_bfloat16 h;
  *reinterpret_cast<unsigned short*>(&h) = u;
  return __bfloat162float(h);
}

// async global->LDS, 16B per lane. LDS dest is wave-uniform base + lane*16.
DEV void gl16(const unsigned short* g, unsigned short* l) {
  __builtin_amdgcn_global_load_lds(
      (const __attribute__((address_space(1))) void*)g,
      (__attribute__((address_space(3))) void*)l, 16, 0, 0);
}

// ---------------- weight transpose + f32->bf16 convert ----------------
// W: (K x N) f32 row-major  ->  WT: (N x K) bf16 row-major
__global__ __launch_bounds__(256) void k_transpose_cvt(
    const float* __restrict__ W, unsigned short* __restrict__ WT, int K, int N) {
  __shared__ float tile[32][33];
  int bk = blockIdx.x * 32, bn = blockIdx.y * 32;
  int tx = threadIdx.x & 31, ty = threadIdx.x >> 5;  // ty 0..7
#pragma unroll
  for (int r = ty; r < 32; r += 8)
    tile[r][tx] = W[(size_t)(bk + r) * N + bn + tx];
  __syncthreads();
#pragma unroll
  for (int r = ty; r < 32; r += 8)
    WT[(size_t)(bn + r) * K + bk + tx] = f2b(tile[tx][r]);
}

// ---------------- LayerNorm (f32 in, bf16 out), one block per row ----------------
__global__ __launch_bounds__(256) void k_layernorm(
    const float* __restrict__ x, const float* __restrict__ sc,
    const float* __restrict__ bi, unsigned short* __restrict__ out) {
  int row = blockIdx.x;
  const float* xr = x + (size_t)row * D_;
  float4 v = reinterpret_cast<const float4*>(xr)[threadIdx.x];
  float s  = v.x + v.y + v.z + v.w;
  float s2 = v.x * v.x + v.y * v.y + v.z * v.z + v.w * v.w;
#pragma unroll
  for (int off = 1; off < 64; off <<= 1) {
    s  += __shfl_xor(s, off);
    s2 += __shfl_xor(s2, off);
  }
  __shared__ float red[2][4];
  int wid = threadIdx.x >> 6;
  if ((threadIdx.x & 63) == 0) { red[0][wid] = s; red[1][wid] = s2; }
  __syncthreads();
  s  = red[0][0] + red[0][1] + red[0][2] + red[0][3];
  s2 = red[1][0] + red[1][1] + red[1][2] + red[1][3];
  float mu  = s * (1.0f / D_);
  float var = s2 * (1.0f / D_) - mu * mu;
  float rstd = rsqrtf(var + 1e-6f);
  int c = threadIdx.x * 4;
  float o0 = (v.x - mu) * rstd * sc[c + 0] + bi[c + 0];
  float o1 = (v.y - mu) * rstd * sc[c + 1] + bi[c + 1];
  float o2 = (v.z - mu) * rstd * sc[c + 2] + bi[c + 2];
  float o3 = (v.w - mu) * rstd * sc[c + 3] + bi[c + 3];
  unsigned short* orow = out + (size_t)row * D_ + c;
  orow[0] = f2b(o0); orow[1] = f2b(o1); orow[2] = f2b(o2); orow[3] = f2b(o3);
}

// ---------------- RoPE in-place on q,k halves of packed qkv (bf16) ----------------
__global__ __launch_bounds__(256) void k_rope(
    unsigned short* __restrict__ qkv, const float* __restrict__ cosp,
    const float* __restrict__ sinp) {
  int idx = blockIdx.x * blockDim.x + threadIdx.x;  // B*T*H*32 pairs
  if (idx >= B_ * T_ * H_ * 32) return;
  int d = idx & 31;
  int h = (idx >> 5) & 15;
  int t = (idx >> 9) & 2047;
  int b = idx >> 20;
  float c  = cosp[t * 32 + d];
  float sn = sinp[t * 32 + d];
  size_t base = ((size_t)(b * T_ + t)) * 3072 + h * 64;
  unsigned short* qp = qkv + base;
  float x1 = b2f(qp[d]), x2 = b2f(qp[d + 32]);
  qp[d]      = f2b(x1 * c - x2 * sn);
  qp[d + 32] = f2b(x2 * c + x1 * sn);
  unsigned short* kp = qkv + base + 1024;
  x1 = b2f(kp[d]); x2 = b2f(kp[d + 32]);
  kp[d]      = f2b(x1 * c - x2 * sn);
  kp[d + 32] = f2b(x2 * c + x1 * sn);
}

// ---------------- V transpose: qkv V-part (B,T,H,hd) -> vT (B*H, hd, T) ------
// Grid: (T/64, B*H). 64 t-rows x 64 d per block.
__global__ __launch_bounds__(256) void k_vtrans(
    const unsigned short* __restrict__ qkv, unsigned short* __restrict__ vT) {
  __shared__ unsigned short tile[64][72];  // [t][d], +8 pad
  int t0 = blockIdx.x * 64, bh = blockIdx.y, b = bh >> 4, h = bh & 15;
  const unsigned short* src = qkv + (size_t)(b * T_ + t0) * 3072 + 2048 + h * 64;
#pragma unroll
  for (int c = 0; c < 2; ++c) {
    int chunk = threadIdx.x + c * 256;          // 512 chunks of 16B... 64*8=512
    int tr = chunk >> 3, d0 = (chunk & 7) * 8;
    uint4 v = *reinterpret_cast<const uint4*>(src + (size_t)tr * 3072 + d0);
    *reinterpret_cast<uint4*>(&tile[tr][d0]) = v;
  }
  __syncthreads();
#pragma unroll
  for (int c = 0; c < 2; ++c) {
    int chunk = threadIdx.x + c * 256;
    int dr = chunk >> 3, tc0 = (chunk & 7) * 8;
    unsigned short tmp[8];
#pragma unroll
    for (int e = 0; e < 8; ++e) tmp[e] = tile[tc0 + e][dr];
    *reinterpret_cast<uint4*>(vT + (size_t)(bh * 64 + dr) * T_ + t0 + tc0) =
        *reinterpret_cast<const uint4*>(tmp);
  }
}

// ---------------- MFMA flash attention, barrier-free ----------------
// Grid: (T/128, B*H), block 256 = 4 independent waves. Wave owns 32 q-rows,
// iterates exactly wr0/64+1 KV tiles (64 keys). K fragments and V^T fragments
// are read DIRECTLY from global (KV is L2/L3-hot; 512 KB per (b,h)) — no
// LDS staging, no V transpose, no __syncthreads. P roundtrips through a
// wave-PRIVATE padded LDS slab (same-wave ordering via lgkmcnt only).
// Mask applied only in the final (diagonal) tile.
__global__ __launch_bounds__(256) void k_attn_mfma(
    const unsigned short* __restrict__ qkv, const unsigned short* __restrict__ vT,
    unsigned short* __restrict__ out) {
  __shared__ __align__(16) unsigned short Pl[4][32][72];
  int bh = blockIdx.y, b = bh >> 4, h = bh & 15;
  int tid = threadIdx.x, lane = tid & 63, w = tid >> 6;
  int wr0 = blockIdx.x * 128 + w * 32;   // wave's first q-row
  int qr = lane & 15, qc = (lane >> 4) * 8;

  // Q fragments (A-layout): [row-tile][k-step]
  bf16x8 qf[2][2];
  const unsigned short* qbase = qkv + (size_t)(b * T_ + wr0) * 3072 + h * 64;
#pragma unroll
  for (int rt = 0; rt < 2; ++rt)
#pragma unroll
    for (int ks = 0; ks < 2; ++ks)
      qf[rt][ks] = *reinterpret_cast<const bf16x8*>(
          qbase + (size_t)(rt * 16 + qr) * 3072 + ks * 32 + qc);

  f32x4 o[2][4] = {};
  float mrow[2][4], lrow[2][4];
#pragma unroll
  for (int rt = 0; rt < 2; ++rt)
#pragma unroll
    for (int r = 0; r < 4; ++r) { mrow[rt][r] = -1e30f; lrow[rt][r] = 0.f; }

  const unsigned short* kbase = qkv + (size_t)b * T_ * 3072 + 1024 + h * 64;
  const unsigned short* vbase = vT + (size_t)(bh * 64) * T_;  // [d][t]
  int ntile = wr0 / 64 + 1;

  for (int jt = 0; jt < ntile; ++jt) {
    int j0 = jt * 64;
    // ---- K fragments from global, S = Q @ K^T ----
    bf16x8 kf[4][2];
#pragma unroll
    for (int ct = 0; ct < 4; ++ct)
#pragma unroll
      for (int ks = 0; ks < 2; ++ks)
        kf[ct][ks] = *reinterpret_cast<const bf16x8*>(
            kbase + (size_t)(j0 + ct * 16 + qr) * 3072 + ks * 32 + qc);
    f32x4 s[2][4];
#pragma unroll
    for (int rt = 0; rt < 2; ++rt)
#pragma unroll
      for (int ct = 0; ct < 4; ++ct) {
        f32x4 acc = {};
#pragma unroll
        for (int ks = 0; ks < 2; ++ks)
          acc = __builtin_amdgcn_mfma_f32_16x16x32_bf16(qf[rt][ks], kf[ct][ks], acc, 0, 0, 0);
        s[rt][ct] = acc;
      }

    // ---- V^T fragments (issue early; consumed after softmax) ----
    bf16x8 vf[4][2];
#pragma unroll
    for (int dt = 0; dt < 4; ++dt)
#pragma unroll
      for (int ks = 0; ks < 2; ++ks)
        vf[dt][ks] = *reinterpret_cast<const bf16x8*>(
            vbase + (size_t)(dt * 16 + qr) * T_ + j0 + ks * 32 + qc);

    // ---- online softmax (C-layout: row=(lane>>4)*4+r, col=lane&15) ----
    bool diag = (jt == ntile - 1);
#pragma unroll
    for (int rt = 0; rt < 2; ++rt) {
#pragma unroll
      for (int r = 0; r < 4; ++r) {
        float mx = -1e30f;
        if (diag) {
          int gi = wr0 + rt * 16 + ((lane >> 4) << 2) + r;
#pragma unroll
          for (int ct = 0; ct < 4; ++ct) {
            int gj = j0 + ct * 16 + (lane & 15);
            float v = s[rt][ct][r] * 0.125f;
            v = (gj <= gi) ? v : -1e30f;
            s[rt][ct][r] = v;
            mx = fmaxf(mx, v);
          }
        } else {
#pragma unroll
          for (int ct = 0; ct < 4; ++ct) {
            float v = s[rt][ct][r] * 0.125f;
            s[rt][ct][r] = v;
            mx = fmaxf(mx, v);
          }
        }
#pragma unroll
        for (int off = 1; off < 16; off <<= 1) mx = fmaxf(mx, __shfl_xor(mx, off));
        float mn = fmaxf(mrow[rt][r], mx);
        float sc = __expf(mrow[rt][r] - mn);
        mrow[rt][r] = mn;
        float rs = 0.f;
#pragma unroll
        for (int ct = 0; ct < 4; ++ct) {
          float p = __expf(s[rt][ct][r] - mn);
          s[rt][ct][r] = p;
          rs += p;
        }
#pragma unroll
        for (int off = 1; off < 16; off <<= 1) rs += __shfl_xor(rs, off);
        lrow[rt][r] = lrow[rt][r] * sc + rs;
#pragma unroll
        for (int dt = 0; dt < 4; ++dt) o[rt][dt][r] *= sc;
      }
    }

    // ---- P -> wave-private LDS (C-layout write, A-layout read), then PV ----
#pragma unroll
    for (int rt = 0; rt < 2; ++rt)
#pragma unroll
      for (int ct = 0; ct < 4; ++ct)
#pragma unroll
        for (int r = 0; r < 4; ++r)
          Pl[w][rt * 16 + ((lane >> 4) << 2) + r][ct * 16 + (lane & 15)] =
              f2b(s[rt][ct][r]);
#pragma unroll
    for (int ks = 0; ks < 2; ++ks) {
#pragma unroll
      for (int rt = 0; rt < 2; ++rt) {
        bf16x8 pf = *reinterpret_cast<const bf16x8*>(&Pl[w][rt * 16 + qr][ks * 32 + qc]);
#pragma unroll
        for (int dt = 0; dt < 4; ++dt)
          o[rt][dt] = __builtin_amdgcn_mfma_f32_16x16x32_bf16(pf, vf[dt][ks], o[rt][dt], 0, 0, 0);
      }
    }
  }

  // ---- write O / l ----
#pragma unroll
  for (int rt = 0; rt < 2; ++rt)
#pragma unroll
    for (int r = 0; r < 4; ++r) {
      float inv = 1.0f / lrow[rt][r];
      size_t grow = (size_t)(b * T_ + wr0 + rt * 16 + ((lane >> 4) << 2) + r);
#pragma unroll
      for (int dt = 0; dt < 4; ++dt)
        out[grow * 1024 + h * 64 + dt * 16 + (lane & 15)] = f2b(o[rt][dt][r] * inv);
    }
}

// ---------------- MFMA GEMM: C(MxN) = A(MxK) @ Bt(NxK)^T, bf16 in, f32 acc ----------
// global_load_lds width-16 staging into LINEAR [128][64] LDS with a both-sides
// involution swizzle: LDS[row][slot] holds global[row][slot ^ (row&7)].
// MODE 0: C = bf16(acc)
// MODE 1: C(f32) = res + acc * gamma[col]
// MODE 2: dual-B: C = bf16( gelu_tanh(accB) * accB2 )
template <int MODE>
__global__ __launch_bounds__(256) void k_gemm(
    const unsigned short* __restrict__ A, const unsigned short* __restrict__ Bt,
    const unsigned short* __restrict__ Bt2, void* __restrict__ Cout,
    const float* __restrict__ res, const float* __restrict__ gamma,
    int M, int N, int K) {
  __shared__ __align__(16) unsigned short Al[128][64];
  __shared__ __align__(16) unsigned short Bl[128][64];
  __shared__ __align__(16) unsigned short Bl2[(MODE == 2) ? 128 : 1][64];
  int m0 = blockIdx.y * 128, n0 = blockIdx.x * 128;
  int tid = threadIdx.x, lane = tid & 63, w = tid >> 6;
  int wm = (w >> 1) * 64, wn = (w & 1) * 64;
  int srow = lane >> 3;
  int scol = ((lane & 7) ^ (lane >> 3)) * 8;
  f32x4 acc[4][4] = {};
  f32x4 acc2[4][4] = {};
  for (int k0 = 0; k0 < K; k0 += 64) {
#pragma unroll
    for (int it = 0; it < 4; ++it) {
      int chunk = w * 4 + it;
      int row = chunk * 8 + srow;
      gl16(A  + (size_t)(m0 + row) * K + k0 + scol, &Al[0][0] + chunk * 512);
      gl16(Bt + (size_t)(n0 + row) * K + k0 + scol, &Bl[0][0] + chunk * 512);
      if constexpr (MODE == 2)
        gl16(Bt2 + (size_t)(n0 + row) * K + k0 + scol, &Bl2[0][0] + chunk * 512);
    }
    __syncthreads();  // compiler drains vmcnt(0) before s_barrier -> tile ready
#pragma unroll
    for (int kk = 0; kk < 2; ++kk) {
      int slotA = ((kk * 4 + (lane >> 4)) ^ (lane & 7)) * 8;
      bf16x8 af[4], bv[4];
#pragma unroll
      for (int i = 0; i < 4; ++i)
        af[i] = *reinterpret_cast<const bf16x8*>(&Al[wm + i * 16 + (lane & 15)][slotA]);
#pragma unroll
      for (int j = 0; j < 4; ++j)
        bv[j] = *reinterpret_cast<const bf16x8*>(&Bl[wn + j * 16 + (lane & 15)][slotA]);
#pragma unroll
      for (int i = 0; i < 4; ++i)
#pragma unroll
        for (int j = 0; j < 4; ++j)
          acc[i][j] = __builtin_amdgcn_mfma_f32_16x16x32_bf16(af[i], bv[j], acc[i][j], 0, 0, 0);
      if constexpr (MODE == 2) {
#pragma unroll
        for (int j = 0; j < 4; ++j)
          bv[j] = *reinterpret_cast<const bf16x8*>(&Bl2[wn + j * 16 + (lane & 15)][slotA]);
#pragma unroll
        for (int i = 0; i < 4; ++i)
#pragma unroll
          for (int j = 0; j < 4; ++j)
            acc2[i][j] = __builtin_amdgcn_mfma_f32_16x16x32_bf16(af[i], bv[j], acc2[i][j], 0, 0, 0);
      }
    }
    __syncthreads();
  }
#pragma unroll
  for (int i = 0; i < 4; ++i) {
#pragma unroll
    for (int j = 0; j < 4; ++j) {
      int row0 = m0 + wm + i * 16 + ((lane >> 4) << 2);
      int col  = n0 + wn + j * 16 + (lane & 15);
#pragma unroll
      for (int r = 0; r < 4; ++r) {
        float va = acc[i][j][r];
        size_t off = (size_t)(row0 + r) * N + col;
        if constexpr (MODE == 0) {
          ((unsigned short*)Cout)[off] = f2b(va);
        } else if constexpr (MODE == 1) {
          ((float*)Cout)[off] = res[off] + va * gamma[col];
        } else {
          float u = acc2[i][j][r];
          float t = tanhf(0.7978845608f * (va + 0.044715f * va * va * va));
          ((unsigned short*)Cout)[off] = f2b(0.5f * va * (1.0f + t) * u);
        }
      }
    }
  }
}

extern "C" void kernel_launch(void* const* d_in, const int* in_sizes, int n_in,
                              void* d_out, int out_size, void* d_ws, size_t ws_size,
                              hipStream_t stream) {
  const float* x      = (const float*)d_in[0];
  const float* cosp   = (const float*)d_in[1];
  const float* sinp   = (const float*)d_in[2];
  const float* ln1s   = (const float*)d_in[3];
  const float* ln1b   = (const float*)d_in[4];
  const float* w_qkv  = (const float*)d_in[5];
  const float* w_o    = (const float*)d_in[6];
  const float* g_attn = (const float*)d_in[7];
  const float* ln2s   = (const float*)d_in[8];
  const float* ln2b   = (const float*)d_in[9];
  const float* w_gate = (const float*)d_in[10];
  const float* w_up   = (const float*)d_in[11];
  const float* w_down = (const float*)d_in[12];
  const float* g_mlp  = (const float*)d_in[13];
  float* outp = (float*)d_out;

  char* ws = (char*)d_ws;
  unsigned short* wqkvT = (unsigned short*)(ws + 0);         // 3072x1024 bf16, 6MB
  unsigned short* woT   = (unsigned short*)(ws + 6291456);   // 1024x1024, 2MB
  unsigned short* wgT   = (unsigned short*)(ws + 8388608);   // 4096x1024, 8MB
  unsigned short* wuT   = (unsigned short*)(ws + 16777216);  // 4096x1024, 8MB
  unsigned short* wdT   = (unsigned short*)(ws + 25165824);  // 1024x4096, 8MB
  float* x2             = (float*)(ws + 33554432);           // 8192x1024 f32, 32MB
  unsigned short* h2    = (unsigned short*)(ws + 67108864);  // 8192x1024, 16MB
  char* big = ws + 83886080;
  unsigned short* hbf     = (unsigned short*)(big);               // 16MB, dead after qkv GEMM
  unsigned short* vT      = (unsigned short*)(big);               // 16MB, reuses hbf slot
  unsigned short* qkv     = (unsigned short*)(big + 16777216);    // 48MB
  unsigned short* attnout = (unsigned short*)(big + 67108864);    // 16MB
  unsigned short* mbuf    = (unsigned short*)(big);               // 64MB, reuses vT/qkv after attn
  // total ws use: 160MB

  // weights -> bf16 transposed
  k_transpose_cvt<<<dim3(32, 96), 256, 0, stream>>>(w_qkv, wqkvT, 1024, 3072);
  k_transpose_cvt<<<dim3(32, 32), 256, 0, stream>>>(w_o, woT, 1024, 1024);
  k_transpose_cvt<<<dim3(32, 128), 256, 0, stream>>>(w_gate, wgT, 1024, 4096);
  k_transpose_cvt<<<dim3(32, 128), 256, 0, stream>>>(w_up, wuT, 1024, 4096);
  k_transpose_cvt<<<dim3(128, 32), 256, 0, stream>>>(w_down, wdT, 4096, 1024);

  // LN1 -> h (bf16)
  k_layernorm<<<M_, 256, 0, stream>>>(x, ln1s, ln1b, hbf);
  // qkv = h @ w_qkv
  k_gemm<0><<<dim3(3072 / 128, M_ / 128), 256, 0, stream>>>(
      hbf, wqkvT, nullptr, qkv, nullptr, nullptr, M_, 3072, 1024);
  // RoPE in-place on q,k
  k_rope<<<16384, 256, 0, stream>>>(qkv, cosp, sinp);
  // V -> vT (B*H, hd, T)   (hbf slot is dead now)
  k_vtrans<<<dim3(T_ / 64, B_ * H_), 256, 0, stream>>>(qkv, vT);
  // barrier-free MFMA flash attention
  k_attn_mfma<<<dim3(T_ / 128, B_ * H_), 256, 0, stream>>>(qkv, vT, attnout);
  // x2 = x + (attnout @ w_o) * gamma_attn
  k_gemm<1><<<dim3(1024 / 128, M_ / 128), 256, 0, stream>>>(
      attnout, woT, nullptr, x2, x, g_attn, M_, 1024, 1024);
  // LN2 -> h2
  k_layernorm<<<M_, 256, 0, stream>>>(x2, ln2s, ln2b, h2);
  // m = gelu(h2@w_gate) * (h2@w_up)
  k_gemm<2><<<dim3(4096 / 128, M_ / 128), 256, 0, stream>>>(
      h2, wgT, wuT, mbuf, nullptr, nullptr, M_, 4096, 1024);
  // out = x2 + (m @ w_down) * gamma_mlp
  k_gemm<1><<<dim3(1024 / 128, M_ / 128), 256, 0, stream>>>(
      mbuf, wdT, nullptr, outp, x2, g_mlp, M_, 1024, 4096);
}